// Round 6
// baseline (575.248 us; speedup 1.0000x reference)
//
#include <hip/hip_runtime.h>
#include <hip/hip_bf16.h>
#include <hip/hip_cooperative_groups.h>
#include <cstdint>

// CapsuleLinear: B=64, I=512, O=64, LIN=8, LOUT=16, 3 routing iterations.
// x: [64,512,8] f32, W: [64,512,16,8] f32, bias: [64,16] f32, out: [64,64,16] f32.
//
// Primary: ONE cooperative kernel, 256 blocks x 512 threads, 1 block/CU
// (=> 2 waves/SIMD => 256-VGPR budget; round-4's spill was the 128-VGPR
// budget of 2 blocks/CU at 512 threads).
//   P: priors[b,i,o,v] = sum_l W[o,i,v,l]*x[b,i,l] -> bf16 ws (2 i's/block)
//   S: each thread loads its 16 priors i-rows (o=lane) ONCE into 128 VGPRs,
//      i-sums -> part0[b][q]  (the only priors read pass)
//   R0..R2: routing iterations entirely from registers (softmax over o via
//      wave shuffle, lane==o, wave=64=O); partials -> part[r+1][b][q]
//   F: squash + bias -> out
// grid.sync() between phases; cross-block data: plain stores before sync,
// agent-scope atomic loads after (round-4-proven visibility pattern).
//
// ws: priors 67,108,864 B | fused part[4][64][4][1024] f32 4 MB |
//     fallback part[4][64][16][1024] f32 16 MB @ +71,303,168.
// Fallback (cooperative launch rejected): verified round-5 pipeline.

typedef float float4v __attribute__((ext_vector_type(4)));
typedef unsigned short ushort8 __attribute__((ext_vector_type(8)));

__device__ __forceinline__ float bf2f(unsigned short u) {
    union { unsigned int ui; float f; } cv;
    cv.ui = ((unsigned int)u) << 16;
    return cv.f;
}
__device__ __forceinline__ unsigned short f2bf(float f) {
    union { float f; unsigned int ui; } cv;
    cv.f = f;
    unsigned int u = cv.ui;
    unsigned int r = u + 0x7FFFu + ((u >> 16) & 1u);  // RNE
    return (unsigned short)(r >> 16);
}

// ===========================================================================
// Fused cooperative kernel
// ===========================================================================
__global__ __launch_bounds__(512, 2) void k_all(const float* __restrict__ W,
                                                const float* __restrict__ x,
                                                const float* __restrict__ bias,
                                                unsigned short* __restrict__ priors,
                                                float* __restrict__ part,
                                                float* __restrict__ out) {
    const int blk = blockIdx.x;   // 0..255
    const int t   = threadIdx.x;  // 0..511

    __shared__ float Wl[2][16 * 132];
    __shared__ float xl[2][512];
    __shared__ float noutT[16 * 64];   // [v][o]
    __shared__ float red[7 * 1088];    // waves 1..7 partials, row pad 17

    // ---------------- phase P: priors for i = blk*2 + (t>>8) ----------------
    {
        const int ih = t >> 8;     // which of the block's two i's
        const int t2 = t & 255;
        const int i  = blk * 2 + ih;

        if (t2 < 128) {
            float4v v = *(const float4v*)(x + ((size_t)(t2 >> 1) * 512 + i) * 8 + (size_t)(t2 & 1) * 4);
            *(float4v*)(xl[ih] + t2 * 4) = v;
        }
        const int r  = t2 & 15;   // o within oc-chunk
        const int bq = t2 >> 4;   // 0..15

        for (int oc = 0; oc < 4; ++oc) {
            __syncthreads();  // uniform: both halves run identical loop
            #pragma unroll
            for (int kk = 0; kk < 2; ++kk) {
                int j  = t2 + kk * 256;
                int ol = j >> 5;
                int r4 = j & 31;
                float4v v = *(const float4v*)(W + ((size_t)((oc * 16 + ol) * 512 + i)) * 128 + (size_t)r4 * 4);
                *(float4v*)(Wl[ih] + ol * 132 + r4 * 4) = v;
            }
            __syncthreads();

            float4v wreg[32];
            const float4v* wp = (const float4v*)(Wl[ih] + r * 132);
            #pragma unroll
            for (int j = 0; j < 32; ++j) wreg[j] = wp[j];

            const int o = oc * 16 + r;
            #pragma unroll
            for (int kk = 0; kk < 4; ++kk) {
                const int b = bq + 16 * kk;
                float4v xr0 = ((const float4v*)(xl[ih] + b * 8))[0];
                float4v xr1 = ((const float4v*)(xl[ih] + b * 8))[1];
                ushort8 u0, u1;
                #pragma unroll
                for (int v = 0; v < 16; ++v) {
                    float s = 0.0f;
                    #pragma unroll
                    for (int l = 0; l < 8; ++l) {
                        int idx = v * 8 + l;
                        float wv = wreg[idx >> 2][idx & 3];
                        float xv = (l < 4) ? xr0[l & 3] : xr1[l & 3];
                        s = fmaf(wv, xv, s);
                    }
                    unsigned short hb = f2bf(s);
                    if (v < 8) u0[v] = hb; else u1[v - 8] = hb;
                }
                unsigned short* dst = priors + ((size_t)(b * 512 + i) * 64 + o) * 16;
                *(ushort8*)(dst) = u0;
                *(ushort8*)(dst + 8) = u1;
            }
        }
    }

    __threadfence();
    cooperative_groups::this_grid().sync();
    asm volatile("" ::: "memory");

    // ---------------- phase S: load fragment + i-sum -> part0 ----------------
    const int b    = blk >> 2;   // 0..63
    const int q    = blk & 3;    // i-quarter (128 i's)
    const int w    = t >> 6;     // wave 0..7
    const int lane = t & 63;     // == o

    ushort8 c0[16], c1[16];      // the thread's 16 priors i-rows (128 VGPRs)
    float acc[16];
    #pragma unroll
    for (int j = 0; j < 16; ++j) acc[j] = 0.0f;

    const unsigned short* bp = priors + (size_t)b * 524288
                             + (size_t)(q * 128 + w * 16) * 1024 + (size_t)lane * 16;
    #pragma unroll
    for (int k = 0; k < 16; ++k) {
        c0[k] = *(const ushort8*)(bp + (size_t)k * 1024);
        c1[k] = *(const ushort8*)(bp + (size_t)k * 1024 + 8);
        #pragma unroll
        for (int j = 0; j < 8; ++j) {
            acc[j]     += bf2f(c0[k][j]);
            acc[8 + j] += bf2f(c1[k][j]);
        }
    }
    if (w > 0) {
        #pragma unroll
        for (int j = 0; j < 16; ++j) red[(w - 1) * 1088 + lane * 17 + j] = acc[j];
    }
    __syncthreads();
    if (w == 0) {
        float* dst = part + (size_t)b * 4096 + (size_t)q * 1024 + lane * 16;
        #pragma unroll
        for (int j = 0; j < 16; ++j) {
            float s = acc[j];
            #pragma unroll
            for (int ww = 0; ww < 7; ++ww) s += red[ww * 1088 + lane * 17 + j];
            dst[j] = s;
        }
    }

    __threadfence();
    cooperative_groups::this_grid().sync();
    asm volatile("" ::: "memory");

    // ---------------- phases R0..R2: routing from registers ----------------
    for (int r = 0; r < 3; ++r) {
        const float* pprev = part + (size_t)r * 262144 + (size_t)b * 4096;
        float*       pnext = part + (size_t)(r + 1) * 262144 + (size_t)b * 4096 + (size_t)q * 1024;

        if (t < 64) {
            float vv[16]; float n2 = 0.0f;
            #pragma unroll
            for (int j = 0; j < 16; ++j) {
                float s = 0.0f;
                #pragma unroll
                for (int ic = 0; ic < 4; ++ic)
                    s += __hip_atomic_load(pprev + ic * 1024 + t * 16 + j,
                                           __ATOMIC_RELAXED, __HIP_MEMORY_SCOPE_AGENT);
                vv[j] = s; n2 += s * s;
            }
            float inv = 1.0f / fmaxf(sqrtf(n2), 1e-12f);
            #pragma unroll
            for (int j = 0; j < 16; ++j) noutT[j * 64 + t] = vv[j] * inv;
        }
        __syncthreads();

        float nr[16];
        #pragma unroll
        for (int j = 0; j < 16; ++j) nr[j] = noutT[j * 64 + lane];

        float a2[16];
        #pragma unroll
        for (int j = 0; j < 16; ++j) a2[j] = 0.0f;

        #pragma unroll
        for (int k = 0; k < 16; ++k) {
            float pf[16];
            #pragma unroll
            for (int j = 0; j < 8; ++j) { pf[j] = bf2f(c0[k][j]); pf[8 + j] = bf2f(c1[k][j]); }

            float logit = 0.0f;
            #pragma unroll
            for (int j = 0; j < 16; ++j) logit = fmaf(pf[j], nr[j], logit);

            float m = logit;
            #pragma unroll
            for (int d = 1; d < 64; d <<= 1) m = fmaxf(m, __shfl_xor(m, d));
            float e = __expf(logit - m);
            float s = e;
            #pragma unroll
            for (int d = 1; d < 64; d <<= 1) s += __shfl_xor(s, d);
            float p = e / s;

            #pragma unroll
            for (int j = 0; j < 16; ++j) a2[j] = fmaf(p, pf[j], a2[j]);
        }

        __syncthreads();  // red free (prev readers done)
        if (w > 0) {
            #pragma unroll
            for (int j = 0; j < 16; ++j) red[(w - 1) * 1088 + lane * 17 + j] = a2[j];
        }
        __syncthreads();
        if (w == 0) {
            #pragma unroll
            for (int j = 0; j < 16; ++j) {
                float s = a2[j];
                #pragma unroll
                for (int ww = 0; ww < 7; ++ww) s += red[ww * 1088 + lane * 17 + j];
                pnext[lane * 16 + j] = s;
            }
        }
        __threadfence();
        cooperative_groups::this_grid().sync();
        asm volatile("" ::: "memory");
    }

    // ---------------- phase F: squash + bias ----------------
    if (q == 0 && t < 64) {
        const float* p3 = part + (size_t)3 * 262144 + (size_t)b * 4096;
        float vv[16]; float n2 = 0.0f;
        #pragma unroll
        for (int j = 0; j < 16; ++j) {
            float s = 0.0f;
            #pragma unroll
            for (int ic = 0; ic < 4; ++ic)
                s += __hip_atomic_load(p3 + ic * 1024 + t * 16 + j,
                                       __ATOMIC_RELAXED, __HIP_MEMORY_SCOPE_AGENT);
            vv[j] = s; n2 += s * s;
        }
        float n = sqrtf(n2);
        float sc = n / (1.0f + n2);
        float* qd = out + (size_t)b * 1024 + t * 16;
        #pragma unroll
        for (int j = 0; j < 16; ++j) qd[j] = vv[j] * sc + bias[t * 16 + j];
    }
}

// ===========================================================================
// Fallback path (verified round-5 pipeline)
// ===========================================================================
__global__ __launch_bounds__(256) void k_priors(const float* __restrict__ W,
                                                const float* __restrict__ x,
                                                unsigned short* __restrict__ priors) {
    const int i = blockIdx.x;
    const int t = threadIdx.x;
    __shared__ float Wl[16 * 132];
    __shared__ float xl[512];

    if (t < 128) {
        float4v v = *(const float4v*)(x + ((size_t)(t >> 1) * 512 + i) * 8 + (size_t)(t & 1) * 4);
        *(float4v*)(xl + t * 4) = v;
    }
    const int r  = t & 15;
    const int bq = t >> 4;

    for (int oc = 0; oc < 4; ++oc) {
        __syncthreads();
        #pragma unroll
        for (int k = 0; k < 2; ++k) {
            int j  = t + k * 256;
            int ol = j >> 5;
            int r4 = j & 31;
            float4v v = *(const float4v*)(W + ((size_t)((oc * 16 + ol) * 512 + i)) * 128 + (size_t)r4 * 4);
            *(float4v*)(Wl + ol * 132 + r4 * 4) = v;
        }
        __syncthreads();

        float4v wreg[32];
        const float4v* wp = (const float4v*)(Wl + r * 132);
        #pragma unroll
        for (int j = 0; j < 32; ++j) wreg[j] = wp[j];

        const int o = oc * 16 + r;
        #pragma unroll
        for (int k = 0; k < 4; ++k) {
            const int b = bq + 16 * k;
            float4v xr0 = ((const float4v*)(xl + b * 8))[0];
            float4v xr1 = ((const float4v*)(xl + b * 8))[1];
            ushort8 u0, u1;
            #pragma unroll
            for (int v = 0; v < 16; ++v) {
                float s = 0.0f;
                #pragma unroll
                for (int l = 0; l < 8; ++l) {
                    int idx = v * 8 + l;
                    float wv = wreg[idx >> 2][idx & 3];
                    float xv = (l < 4) ? xr0[l & 3] : xr1[l & 3];
                    s = fmaf(wv, xv, s);
                }
                unsigned short hb = f2bf(s);
                if (v < 8) u0[v] = hb; else u1[v - 8] = hb;
            }
            unsigned short* dst = priors + ((size_t)(b * 512 + i) * 64 + o) * 16;
            *(ushort8*)(dst) = u0;
            *(ushort8*)(dst + 8) = u1;
        }
    }
}

__global__ __launch_bounds__(256) void k_sum0(const unsigned short* __restrict__ priors,
                                              float* __restrict__ part0) {
    const int b    = blockIdx.x >> 4;
    const int ic   = blockIdx.x & 15;
    const int t    = threadIdx.x;
    const int slot = t & 127;
    const int io   = t >> 7;
    const int o    = slot >> 1;
    const int vh   = slot & 1;

    float acc[8];
    #pragma unroll
    for (int j = 0; j < 8; ++j) acc[j] = 0.0f;

    const unsigned short* base = priors + (size_t)b * 524288 + (size_t)o * 16 + vh * 8;
    #pragma unroll
    for (int k = 0; k < 16; ++k) {
        const int i = ic * 32 + k * 2 + io;
        ushort8 u = *(const ushort8*)(base + (size_t)i * 1024);
        #pragma unroll
        for (int j = 0; j < 8; ++j) acc[j] += bf2f(u[j]);
    }

    __shared__ float red[8 * 128];
    if (io == 1) {
        #pragma unroll
        for (int j = 0; j < 8; ++j) red[j * 128 + slot] = acc[j];
    }
    __syncthreads();
    if (io == 0) {
        float* dst = part0 + (size_t)b * 16384 + (size_t)ic * 1024 + o * 16 + vh * 8;
        #pragma unroll
        for (int j = 0; j < 8; ++j) dst[j] = acc[j] + red[j * 128 + slot];
    }
}

__global__ __launch_bounds__(256) void k_route(const unsigned short* __restrict__ priors,
                                               const float* __restrict__ part_prev,
                                               float* __restrict__ part_next) {
    const int b    = blockIdx.x >> 4;
    const int h    = blockIdx.x & 15;
    const int t    = threadIdx.x;
    const int w    = t >> 6;
    const int lane = t & 63;

    __shared__ float noutT[16 * 64];
    __shared__ float accbuf[4 * 1088];

    if (t < 64) {
        const float* pp = part_prev + (size_t)b * 16384 + t * 16;
        float4v s4[4];
        #pragma unroll
        for (int g = 0; g < 4; ++g) s4[g] = (float4v){0.f, 0.f, 0.f, 0.f};
        #pragma unroll
        for (int ic = 0; ic < 16; ++ic) {
            #pragma unroll
            for (int g = 0; g < 4; ++g)
                s4[g] += *(const float4v*)(pp + (size_t)ic * 1024 + g * 4);
        }
        float vv[16]; float n2 = 0.0f;
        #pragma unroll
        for (int j = 0; j < 16; ++j) { vv[j] = s4[j >> 2][j & 3]; n2 += vv[j] * vv[j]; }
        float inv = 1.0f / fmaxf(sqrtf(n2), 1e-12f);
        #pragma unroll
        for (int j = 0; j < 16; ++j) noutT[j * 64 + t] = vv[j] * inv;
    }
    __syncthreads();

    float nr[16];
    #pragma unroll
    for (int j = 0; j < 16; ++j) nr[j] = noutT[j * 64 + lane];

    float acc[16];
    #pragma unroll
    for (int j = 0; j < 16; ++j) acc[j] = 0.0f;

    const size_t base = (size_t)b * 524288 + (size_t)lane * 16;
    #pragma unroll
    for (int k = 0; k < 8; ++k) {
        const int i = h * 32 + w + 4 * k;
        const ushort8* pp = (const ushort8*)(priors + base + (size_t)i * 1024);
        ushort8 u0 = pp[0], u1 = pp[1];
        float pf[16];
        #pragma unroll
        for (int j = 0; j < 8; ++j) { pf[j] = bf2f(u0[j]); pf[8 + j] = bf2f(u1[j]); }

        float logit = 0.0f;
        #pragma unroll
        for (int j = 0; j < 16; ++j) logit = fmaf(pf[j], nr[j], logit);

        float m = logit;
        #pragma unroll
        for (int d = 1; d < 64; d <<= 1) m = fmaxf(m, __shfl_xor(m, d));
        float e = __expf(logit - m);
        float s = e;
        #pragma unroll
        for (int d = 1; d < 64; d <<= 1) s += __shfl_xor(s, d);
        float p = e / s;

        #pragma unroll
        for (int j = 0; j < 16; ++j) acc[j] = fmaf(p, pf[j], acc[j]);
    }

    #pragma unroll
    for (int j = 0; j < 16; ++j) accbuf[w * 1088 + lane * 17 + j] = acc[j];
    __syncthreads();

    float* dst = part_next + (size_t)b * 16384 + (size_t)h * 1024;
    for (int j = t; j < 1024; j += 256) {
        const int o = j >> 4, v = j & 15;
        const int idx = o * 17 + v;
        dst[j] = accbuf[idx] + accbuf[1088 + idx] + accbuf[2176 + idx] + accbuf[3264 + idx];
    }
}

__global__ __launch_bounds__(64) void k_fin(const float* __restrict__ part3,
                                            const float* __restrict__ bias,
                                            float* __restrict__ out) {
    const int b = blockIdx.x;
    const int o = threadIdx.x;
    const float* pp = part3 + (size_t)b * 16384 + o * 16;
    float4v s4[4];
    #pragma unroll
    for (int g = 0; g < 4; ++g) s4[g] = (float4v){0.f, 0.f, 0.f, 0.f};
    #pragma unroll
    for (int ic = 0; ic < 16; ++ic) {
        #pragma unroll
        for (int g = 0; g < 4; ++g)
            s4[g] += *(const float4v*)(pp + (size_t)ic * 1024 + g * 4);
    }
    float vv[16]; float n2 = 0.0f;
    #pragma unroll
    for (int j = 0; j < 16; ++j) { vv[j] = s4[j >> 2][j & 3]; n2 += vv[j] * vv[j]; }
    float n = sqrtf(n2);
    float scale = n / (1.0f + n2);
    float* q = out + (size_t)b * 1024 + o * 16;
    #pragma unroll
    for (int j = 0; j < 16; ++j) q[j] = vv[j] * scale + bias[o * 16 + j];
}

extern "C" void kernel_launch(void* const* d_in, const int* in_sizes, int n_in,
                              void* d_out, int out_size, void* d_ws, size_t ws_size,
                              hipStream_t stream) {
    const float* x    = (const float*)d_in[0];   // [64,512,8]
    const float* W    = (const float*)d_in[1];   // [64,512,16,8]
    const float* bias = (const float*)d_in[2];   // [64,16]
    float* out = (float*)d_out;                  // [64,64,16]

    unsigned short* priors = (unsigned short*)d_ws;                        // 67,108,864 B
    float* partF = (float*)((char*)d_ws + 67108864);                       // 4 x 262144 f32 (fused)
    float* partB = (float*)((char*)d_ws + 71303168);                       // 4 x 1048576 f32 (fallback)

    void* args[] = { (void*)&W, (void*)&x, (void*)&bias, (void*)&priors,
                     (void*)&partF, (void*)&out };
    hipError_t err = hipLaunchCooperativeKernel((const void*)k_all, dim3(256), dim3(512),
                                                args, 0, stream);
    if (err != hipSuccess) {
        (void)hipGetLastError();  // clear error state
        float* p0 = partB;
        float* p1 = partB + 1048576;
        float* p2 = partB + 2 * 1048576;
        float* p3 = partB + 3 * 1048576;
        k_priors<<<512, 256, 0, stream>>>(W, x, priors);
        k_sum0  <<<1024, 256, 0, stream>>>(priors, p0);
        k_route <<<1024, 256, 0, stream>>>(priors, p0, p1);
        k_route <<<1024, 256, 0, stream>>>(priors, p1, p2);
        k_route <<<1024, 256, 0, stream>>>(priors, p2, p3);
        k_fin   <<<64, 64, 0, stream>>>(p3, bias, out);
    }
}

// Round 7
// 393.822 us; speedup vs baseline: 1.4607x; 1.4607x over previous
//
#include <hip/hip_runtime.h>
#include <hip/hip_bf16.h>
#include <hip/hip_cooperative_groups.h>
#include <cstdint>

// CapsuleLinear: B=64, I=512, O=64, LIN=8, LOUT=16, 3 routing iterations.
// x: [64,512,8] f32, W: [64,512,16,8] f32, bias: [64,16] f32, out: [64,64,16] f32.
//
// Primary: ONE kernel, 256 blocks x 512 threads, co-residency validated by
// hipLaunchCooperativeKernel, but grid sync is HAND-ROLLED (inline atomics,
// no calls) so the 512B/thread priors fragment stays in VGPRs across phases.
// Round-4/6 post-mortem: this_grid().sync() is an ABI call -> everything
// live across it was spilled to scratch (134MB excess WRITE_SIZE, VGPR=128).
//   P:  priors[b,i,o,v] = sum_l W[o,i,v,l]*x[b,i,l] -> bf16 ws (2 i/block)
//   S:  each thread loads its 16 priors i-rows (o=lane) ONCE into 128 VGPRs,
//       i-sums -> part0[b][q]   (the only priors read pass)
//   R0..R2: routing iterations entirely from registers (softmax over o via
//       wave shuffle, lane==o, wave=64=O); partials -> part[r+1][b][q]
//   F:  squash + bias -> out
// Barrier: monotonic arrive-counter + generation word in ws, zeroed per
// launch via hipMemsetAsync (graph-legal). Agent-scope atomics/fences per
// XCD non-coherence rules; plain bulk loads after the handshake were proven
// correct by rounds 4/6 on this chip.
//
// ws: priors 67,108,864 B | fused part [4][64][4][1024] f32 = 4 MB |
//     barrier 8 B @ +71,303,168 | fallback partB 16 MB @ +67,108,864
//     (fallback and fused part regions are mutually exclusive).
// Fallback (coop launch rejected): verified round-5 pipeline (~106us).

typedef float float4v __attribute__((ext_vector_type(4)));
typedef unsigned short ushort8 __attribute__((ext_vector_type(8)));

#define NBLK 256

__device__ __forceinline__ float bf2f(unsigned short u) {
    union { unsigned int ui; float f; } cv;
    cv.ui = ((unsigned int)u) << 16;
    return cv.f;
}
__device__ __forceinline__ unsigned short f2bf(float f) {
    union { float f; unsigned int ui; } cv;
    cv.f = f;
    unsigned int u = cv.ui;
    unsigned int r = u + 0x7FFFu + ((u >> 16) & 1u);  // RNE
    return (unsigned short)(r >> 16);
}

// Hand-rolled grid barrier: no calls, monotonic counter (no reset race).
// phase is 1-based and strictly increasing within the kernel.
__device__ __forceinline__ void gbar(int* cnt, int* gen, int phase) {
    __syncthreads();
    if (threadIdx.x == 0) {
        __threadfence();  // agent-scope release of prior writes
        int old = __hip_atomic_fetch_add(cnt, 1, __ATOMIC_ACQ_REL,
                                         __HIP_MEMORY_SCOPE_AGENT);
        if (old == phase * NBLK - 1) {
            __hip_atomic_store(gen, phase, __ATOMIC_RELEASE,
                               __HIP_MEMORY_SCOPE_AGENT);
        } else {
            while (__hip_atomic_load(gen, __ATOMIC_ACQUIRE,
                                     __HIP_MEMORY_SCOPE_AGENT) < phase) {
                __builtin_amdgcn_s_sleep(2);
            }
        }
    }
    __syncthreads();
}

// ===========================================================================
// Fused kernel (no external calls anywhere -> fragment stays in VGPRs)
// ===========================================================================
__global__ __launch_bounds__(512, 2) void k_all(const float* __restrict__ W,
                                                const float* __restrict__ x,
                                                const float* __restrict__ bias,
                                                unsigned short* __restrict__ priors,
                                                float* __restrict__ part,
                                                float* __restrict__ out,
                                                int* __restrict__ bar) {
    const int blk = blockIdx.x;   // 0..255
    const int t   = threadIdx.x;  // 0..511
    int* cnt = bar;
    int* gen = bar + 1;

    __shared__ float Wl[2][16 * 132];
    __shared__ float xl[2][512];
    __shared__ float noutT[16 * 64];   // [v][o]
    __shared__ float red[7 * 1088];    // waves 1..7 partials, row pad 17

    // ---------------- phase P: priors for i = blk*2 + (t>>8) ----------------
    {
        const int ih = t >> 8;     // which of the block's two i's
        const int t2 = t & 255;
        const int i  = blk * 2 + ih;

        if (t2 < 128) {
            float4v v = *(const float4v*)(x + ((size_t)(t2 >> 1) * 512 + i) * 8 + (size_t)(t2 & 1) * 4);
            *(float4v*)(xl[ih] + t2 * 4) = v;
        }
        const int r  = t2 & 15;   // o within oc-chunk
        const int bq = t2 >> 4;   // 0..15

        for (int oc = 0; oc < 4; ++oc) {
            __syncthreads();  // uniform across both halves
            #pragma unroll
            for (int kk = 0; kk < 2; ++kk) {
                int j  = t2 + kk * 256;
                int ol = j >> 5;
                int r4 = j & 31;
                float4v v = *(const float4v*)(W + ((size_t)((oc * 16 + ol) * 512 + i)) * 128 + (size_t)r4 * 4);
                *(float4v*)(Wl[ih] + ol * 132 + r4 * 4) = v;
            }
            __syncthreads();

            float4v wreg[32];
            const float4v* wp = (const float4v*)(Wl[ih] + r * 132);
            #pragma unroll
            for (int j = 0; j < 32; ++j) wreg[j] = wp[j];

            const int o = oc * 16 + r;
            #pragma unroll
            for (int kk = 0; kk < 4; ++kk) {
                const int b = bq + 16 * kk;
                float4v xr0 = ((const float4v*)(xl[ih] + b * 8))[0];
                float4v xr1 = ((const float4v*)(xl[ih] + b * 8))[1];
                ushort8 u0, u1;
                #pragma unroll
                for (int v = 0; v < 16; ++v) {
                    float s = 0.0f;
                    #pragma unroll
                    for (int l = 0; l < 8; ++l) {
                        int idx = v * 8 + l;
                        float wv = wreg[idx >> 2][idx & 3];
                        float xv = (l < 4) ? xr0[l & 3] : xr1[l & 3];
                        s = fmaf(wv, xv, s);
                    }
                    unsigned short hb = f2bf(s);
                    if (v < 8) u0[v] = hb; else u1[v - 8] = hb;
                }
                unsigned short* dst = priors + ((size_t)(b * 512 + i) * 64 + o) * 16;
                *(ushort8*)(dst) = u0;
                *(ushort8*)(dst + 8) = u1;
            }
        }
    }

    gbar(cnt, gen, 1);

    // ---------------- phase S: load fragment + i-sum -> part0 ----------------
    const int b    = blk >> 2;   // 0..63
    const int q    = blk & 3;    // i-quarter (128 i's)
    const int w    = t >> 6;     // wave 0..7
    const int lane = t & 63;     // == o

    ushort8 c0[16], c1[16];      // the thread's 16 priors i-rows (128 VGPRs)
    float acc[16];
    #pragma unroll
    for (int j = 0; j < 16; ++j) acc[j] = 0.0f;

    const unsigned short* bp = priors + (size_t)b * 524288
                             + (size_t)(q * 128 + w * 16) * 1024 + (size_t)lane * 16;
    #pragma unroll
    for (int k = 0; k < 16; ++k) {
        c0[k] = *(const ushort8*)(bp + (size_t)k * 1024);
        c1[k] = *(const ushort8*)(bp + (size_t)k * 1024 + 8);
        #pragma unroll
        for (int j = 0; j < 8; ++j) {
            acc[j]     += bf2f(c0[k][j]);
            acc[8 + j] += bf2f(c1[k][j]);
        }
    }
    if (w > 0) {
        #pragma unroll
        for (int j = 0; j < 16; ++j) red[(w - 1) * 1088 + lane * 17 + j] = acc[j];
    }
    __syncthreads();
    if (w == 0) {
        float* dst = part + (size_t)b * 4096 + (size_t)q * 1024 + lane * 16;
        #pragma unroll
        for (int j = 0; j < 16; ++j) {
            float s = acc[j];
            #pragma unroll
            for (int ww = 0; ww < 7; ++ww) s += red[ww * 1088 + lane * 17 + j];
            dst[j] = s;
        }
    }

    gbar(cnt, gen, 2);

    // ---------------- phases R0..R2: routing from registers ----------------
    for (int r = 0; r < 3; ++r) {
        const float* pprev = part + (size_t)r * 262144 + (size_t)b * 4096;
        float*       pnext = part + (size_t)(r + 1) * 262144 + (size_t)b * 4096 + (size_t)q * 1024;

        if (t < 64) {
            float vv[16]; float n2 = 0.0f;
            #pragma unroll
            for (int j = 0; j < 16; ++j) {
                float s = 0.0f;
                #pragma unroll
                for (int ic = 0; ic < 4; ++ic)
                    s += __hip_atomic_load(pprev + ic * 1024 + t * 16 + j,
                                           __ATOMIC_RELAXED, __HIP_MEMORY_SCOPE_AGENT);
                vv[j] = s; n2 += s * s;
            }
            float inv = 1.0f / fmaxf(sqrtf(n2), 1e-12f);
            #pragma unroll
            for (int j = 0; j < 16; ++j) noutT[j * 64 + t] = vv[j] * inv;
        }
        __syncthreads();

        float nr[16];
        #pragma unroll
        for (int j = 0; j < 16; ++j) nr[j] = noutT[j * 64 + lane];

        float a2[16];
        #pragma unroll
        for (int j = 0; j < 16; ++j) a2[j] = 0.0f;

        #pragma unroll
        for (int k = 0; k < 16; ++k) {
            float pf[16];
            #pragma unroll
            for (int j = 0; j < 8; ++j) { pf[j] = bf2f(c0[k][j]); pf[8 + j] = bf2f(c1[k][j]); }

            float logit = 0.0f;
            #pragma unroll
            for (int j = 0; j < 16; ++j) logit = fmaf(pf[j], nr[j], logit);

            float m = logit;
            #pragma unroll
            for (int d = 1; d < 64; d <<= 1) m = fmaxf(m, __shfl_xor(m, d));
            float e = __expf(logit - m);
            float s = e;
            #pragma unroll
            for (int d = 1; d < 64; d <<= 1) s += __shfl_xor(s, d);
            float p = e / s;

            #pragma unroll
            for (int j = 0; j < 16; ++j) a2[j] = fmaf(p, pf[j], a2[j]);
        }

        __syncthreads();  // red free (prev readers done)
        if (w > 0) {
            #pragma unroll
            for (int j = 0; j < 16; ++j) red[(w - 1) * 1088 + lane * 17 + j] = a2[j];
        }
        __syncthreads();
        if (w == 0) {
            #pragma unroll
            for (int j = 0; j < 16; ++j) {
                float s = a2[j];
                #pragma unroll
                for (int ww = 0; ww < 7; ++ww) s += red[ww * 1088 + lane * 17 + j];
                pnext[lane * 16 + j] = s;
            }
        }
        gbar(cnt, gen, 3 + r);
    }

    // ---------------- phase F: squash + bias ----------------
    if (q == 0 && t < 64) {
        const float* p3 = part + (size_t)3 * 262144 + (size_t)b * 4096;
        float vv[16]; float n2 = 0.0f;
        #pragma unroll
        for (int j = 0; j < 16; ++j) {
            float s = 0.0f;
            #pragma unroll
            for (int ic = 0; ic < 4; ++ic)
                s += __hip_atomic_load(p3 + ic * 1024 + t * 16 + j,
                                       __ATOMIC_RELAXED, __HIP_MEMORY_SCOPE_AGENT);
            vv[j] = s; n2 += s * s;
        }
        float n = sqrtf(n2);
        float sc = n / (1.0f + n2);
        float* qd = out + (size_t)b * 1024 + t * 16;
        #pragma unroll
        for (int j = 0; j < 16; ++j) qd[j] = vv[j] * sc + bias[t * 16 + j];
    }
}

// ===========================================================================
// Fallback path (verified round-5 pipeline)
// ===========================================================================
__global__ __launch_bounds__(256) void k_priors(const float* __restrict__ W,
                                                const float* __restrict__ x,
                                                unsigned short* __restrict__ priors) {
    const int i = blockIdx.x;
    const int t = threadIdx.x;
    __shared__ float Wl[16 * 132];
    __shared__ float xl[512];

    if (t < 128) {
        float4v v = *(const float4v*)(x + ((size_t)(t >> 1) * 512 + i) * 8 + (size_t)(t & 1) * 4);
        *(float4v*)(xl + t * 4) = v;
    }
    const int r  = t & 15;
    const int bq = t >> 4;

    for (int oc = 0; oc < 4; ++oc) {
        __syncthreads();
        #pragma unroll
        for (int k = 0; k < 2; ++k) {
            int j  = t + k * 256;
            int ol = j >> 5;
            int r4 = j & 31;
            float4v v = *(const float4v*)(W + ((size_t)((oc * 16 + ol) * 512 + i)) * 128 + (size_t)r4 * 4);
            *(float4v*)(Wl + ol * 132 + r4 * 4) = v;
        }
        __syncthreads();

        float4v wreg[32];
        const float4v* wp = (const float4v*)(Wl + r * 132);
        #pragma unroll
        for (int j = 0; j < 32; ++j) wreg[j] = wp[j];

        const int o = oc * 16 + r;
        #pragma unroll
        for (int k = 0; k < 4; ++k) {
            const int b = bq + 16 * k;
            float4v xr0 = ((const float4v*)(xl + b * 8))[0];
            float4v xr1 = ((const float4v*)(xl + b * 8))[1];
            ushort8 u0, u1;
            #pragma unroll
            for (int v = 0; v < 16; ++v) {
                float s = 0.0f;
                #pragma unroll
                for (int l = 0; l < 8; ++l) {
                    int idx = v * 8 + l;
                    float wv = wreg[idx >> 2][idx & 3];
                    float xv = (l < 4) ? xr0[l & 3] : xr1[l & 3];
                    s = fmaf(wv, xv, s);
                }
                unsigned short hb = f2bf(s);
                if (v < 8) u0[v] = hb; else u1[v - 8] = hb;
            }
            unsigned short* dst = priors + ((size_t)(b * 512 + i) * 64 + o) * 16;
            *(ushort8*)(dst) = u0;
            *(ushort8*)(dst + 8) = u1;
        }
    }
}

__global__ __launch_bounds__(256) void k_sum0(const unsigned short* __restrict__ priors,
                                              float* __restrict__ part0) {
    const int b    = blockIdx.x >> 4;
    const int ic   = blockIdx.x & 15;
    const int t    = threadIdx.x;
    const int slot = t & 127;
    const int io   = t >> 7;
    const int o    = slot >> 1;
    const int vh   = slot & 1;

    float acc[8];
    #pragma unroll
    for (int j = 0; j < 8; ++j) acc[j] = 0.0f;

    const unsigned short* base = priors + (size_t)b * 524288 + (size_t)o * 16 + vh * 8;
    #pragma unroll
    for (int k = 0; k < 16; ++k) {
        const int i = ic * 32 + k * 2 + io;
        ushort8 u = *(const ushort8*)(base + (size_t)i * 1024);
        #pragma unroll
        for (int j = 0; j < 8; ++j) acc[j] += bf2f(u[j]);
    }

    __shared__ float red[8 * 128];
    if (io == 1) {
        #pragma unroll
        for (int j = 0; j < 8; ++j) red[j * 128 + slot] = acc[j];
    }
    __syncthreads();
    if (io == 0) {
        float* dst = part0 + (size_t)b * 16384 + (size_t)ic * 1024 + o * 16 + vh * 8;
        #pragma unroll
        for (int j = 0; j < 8; ++j) dst[j] = acc[j] + red[j * 128 + slot];
    }
}

__global__ __launch_bounds__(256) void k_route(const unsigned short* __restrict__ priors,
                                               const float* __restrict__ part_prev,
                                               float* __restrict__ part_next) {
    const int b    = blockIdx.x >> 4;
    const int h    = blockIdx.x & 15;
    const int t    = threadIdx.x;
    const int w    = t >> 6;
    const int lane = t & 63;

    __shared__ float noutT[16 * 64];
    __shared__ float accbuf[4 * 1088];

    if (t < 64) {
        const float* pp = part_prev + (size_t)b * 16384 + t * 16;
        float4v s4[4];
        #pragma unroll
        for (int g = 0; g < 4; ++g) s4[g] = (float4v){0.f, 0.f, 0.f, 0.f};
        #pragma unroll
        for (int ic = 0; ic < 16; ++ic) {
            #pragma unroll
            for (int g = 0; g < 4; ++g)
                s4[g] += *(const float4v*)(pp + (size_t)ic * 1024 + g * 4);
        }
        float vv[16]; float n2 = 0.0f;
        #pragma unroll
        for (int j = 0; j < 16; ++j) { vv[j] = s4[j >> 2][j & 3]; n2 += vv[j] * vv[j]; }
        float inv = 1.0f / fmaxf(sqrtf(n2), 1e-12f);
        #pragma unroll
        for (int j = 0; j < 16; ++j) noutT[j * 64 + t] = vv[j] * inv;
    }
    __syncthreads();

    float nr[16];
    #pragma unroll
    for (int j = 0; j < 16; ++j) nr[j] = noutT[j * 64 + lane];

    float acc[16];
    #pragma unroll
    for (int j = 0; j < 16; ++j) acc[j] = 0.0f;

    const size_t base = (size_t)b * 524288 + (size_t)lane * 16;
    #pragma unroll
    for (int k = 0; k < 8; ++k) {
        const int i = h * 32 + w + 4 * k;
        const ushort8* pp = (const ushort8*)(priors + base + (size_t)i * 1024);
        ushort8 u0 = pp[0], u1 = pp[1];
        float pf[16];
        #pragma unroll
        for (int j = 0; j < 8; ++j) { pf[j] = bf2f(u0[j]); pf[8 + j] = bf2f(u1[j]); }

        float logit = 0.0f;
        #pragma unroll
        for (int j = 0; j < 16; ++j) logit = fmaf(pf[j], nr[j], logit);

        float m = logit;
        #pragma unroll
        for (int d = 1; d < 64; d <<= 1) m = fmaxf(m, __shfl_xor(m, d));
        float e = __expf(logit - m);
        float s = e;
        #pragma unroll
        for (int d = 1; d < 64; d <<= 1) s += __shfl_xor(s, d);
        float p = e / s;

        #pragma unroll
        for (int j = 0; j < 16; ++j) acc[j] = fmaf(p, pf[j], acc[j]);
    }

    #pragma unroll
    for (int j = 0; j < 16; ++j) accbuf[w * 1088 + lane * 17 + j] = acc[j];
    __syncthreads();

    float* dst = part_next + (size_t)b * 16384 + (size_t)h * 1024;
    for (int j = t; j < 1024; j += 256) {
        const int o = j >> 4, v = j & 15;
        const int idx = o * 17 + v;
        dst[j] = accbuf[idx] + accbuf[1088 + idx] + accbuf[2176 + idx] + accbuf[3264 + idx];
    }
}

__global__ __launch_bounds__(64) void k_fin(const float* __restrict__ part3,
                                            const float* __restrict__ bias,
                                            float* __restrict__ out) {
    const int b = blockIdx.x;
    const int o = threadIdx.x;
    const float* pp = part3 + (size_t)b * 16384 + o * 16;
    float4v s4[4];
    #pragma unroll
    for (int g = 0; g < 4; ++g) s4[g] = (float4v){0.f, 0.f, 0.f, 0.f};
    #pragma unroll
    for (int ic = 0; ic < 16; ++ic) {
        #pragma unroll
        for (int g = 0; g < 4; ++g)
            s4[g] += *(const float4v*)(pp + (size_t)ic * 1024 + g * 4);
    }
    float vv[16]; float n2 = 0.0f;
    #pragma unroll
    for (int j = 0; j < 16; ++j) { vv[j] = s4[j >> 2][j & 3]; n2 += vv[j] * vv[j]; }
    float n = sqrtf(n2);
    float scale = n / (1.0f + n2);
    float* q = out + (size_t)b * 1024 + o * 16;
    #pragma unroll
    for (int j = 0; j < 16; ++j) q[j] = vv[j] * scale + bias[o * 16 + j];
}

extern "C" void kernel_launch(void* const* d_in, const int* in_sizes, int n_in,
                              void* d_out, int out_size, void* d_ws, size_t ws_size,
                              hipStream_t stream) {
    const float* x    = (const float*)d_in[0];   // [64,512,8]
    const float* W    = (const float*)d_in[1];   // [64,512,16,8]
    const float* bias = (const float*)d_in[2];   // [64,16]
    float* out = (float*)d_out;                  // [64,64,16]

    unsigned short* priors = (unsigned short*)d_ws;                 // 67,108,864 B
    float* partF = (float*)((char*)d_ws + 67108864);                // 4 MB (fused)
    int*   bar   = (int*)((char*)d_ws + 71303168);                  // 8 B barrier
    float* partB = (float*)((char*)d_ws + 67108864);                // 16 MB (fallback; exclusive)

    // zero the barrier words each launch (graph-legal, deterministic)
    hipMemsetAsync(bar, 0, 8, stream);

    void* args[] = { (void*)&W, (void*)&x, (void*)&bias, (void*)&priors,
                     (void*)&partF, (void*)&out, (void*)&bar };
    hipError_t err = hipLaunchCooperativeKernel((const void*)k_all, dim3(256), dim3(512),
                                                args, 0, stream);
    if (err != hipSuccess) {
        (void)hipGetLastError();  // clear error state
        float* p0 = partB;
        float* p1 = partB + 1048576;
        float* p2 = partB + 2 * 1048576;
        float* p3 = partB + 3 * 1048576;
        k_priors<<<512, 256, 0, stream>>>(W, x, priors);
        k_sum0  <<<1024, 256, 0, stream>>>(priors, p0);
        k_route <<<1024, 256, 0, stream>>>(priors, p0, p1);
        k_route <<<1024, 256, 0, stream>>>(priors, p1, p2);
        k_route <<<1024, 256, 0, stream>>>(priors, p2, p3);
        k_fin   <<<64, 64, 0, stream>>>(p3, bias, out);
    }
}

// Round 8
// 384.175 us; speedup vs baseline: 1.4974x; 1.0251x over previous
//
#include <hip/hip_runtime.h>
#include <hip/hip_bf16.h>
#include <hip/hip_cooperative_groups.h>
#include <cstdint>

// CapsuleLinear: B=64, I=512, O=64, LIN=8, LOUT=16, 3 routing iterations.
// x: [64,512,8] f32, W: [64,512,16,8] f32, bias: [64,16] f32, out: [64,64,16] f32.
//
// ONE kernel, 256 blocks x 512 threads, 1 block/CU.
// KEY FIX (round 8): __launch_bounds__(512, 1) -- the second arg behaves as
// min-BLOCKS-per-CU (CUDA semantics): rounds 4/6/7 used (512,2) => 16 waves/CU
// => 4 waves/SIMD => hard 128-VGPR cap => the 512B/thread priors fragment
// spilled to scratch every phase (~130MB excess WRITE_SIZE, VGPR_Count=128).
// (512,1) => 8 waves/CU => 2 waves/SIMD => 256-VGPR cap; live set ~225 fits.
//   P:  priors[b,i,o,v] = sum_l W[o,i,v,l]*x[b,i,l] -> bf16 ws (2 i/block)
//   S:  each thread loads its 16 priors i-rows (o=lane) ONCE into 128 VGPRs,
//       i-sums -> part0[b][q]   (the only priors read pass)
//   R0..R2: routing iterations entirely from registers (softmax over o via
//       wave shuffle, lane==o, wave=64=O); partials -> part[r+1][b][q]
//   F:  squash + bias -> out
// Grid barrier: hand-rolled monotonic counter (inline atomics, no calls),
// zeroed per launch via hipMemsetAsync (graph-legal). Agent-scope
// atomics/fences per XCD non-coherence rules.
//
// ws: priors 67,108,864 B | fused part [4][64][4][1024] f32 = 4 MB |
//     barrier 8 B @ +71,303,168 | fallback partB 16 MB @ +67,108,864
//     (fallback and fused part regions are mutually exclusive).
// Fallback (coop launch rejected): verified round-5 pipeline (~106us).

typedef float float4v __attribute__((ext_vector_type(4)));
typedef unsigned short ushort8 __attribute__((ext_vector_type(8)));

#define NBLK 256

__device__ __forceinline__ float bf2f(unsigned short u) {
    union { unsigned int ui; float f; } cv;
    cv.ui = ((unsigned int)u) << 16;
    return cv.f;
}
__device__ __forceinline__ unsigned short f2bf(float f) {
    union { float f; unsigned int ui; } cv;
    cv.f = f;
    unsigned int u = cv.ui;
    unsigned int r = u + 0x7FFFu + ((u >> 16) & 1u);  // RNE
    return (unsigned short)(r >> 16);
}

// Hand-rolled grid barrier: no calls, monotonic counter (no reset race).
// phase is 1-based and strictly increasing within the kernel.
__device__ __forceinline__ void gbar(int* cnt, int* gen, int phase) {
    __syncthreads();
    if (threadIdx.x == 0) {
        __threadfence();  // agent-scope release of prior writes
        int old = __hip_atomic_fetch_add(cnt, 1, __ATOMIC_ACQ_REL,
                                         __HIP_MEMORY_SCOPE_AGENT);
        if (old == phase * NBLK - 1) {
            __hip_atomic_store(gen, phase, __ATOMIC_RELEASE,
                               __HIP_MEMORY_SCOPE_AGENT);
        } else {
            while (__hip_atomic_load(gen, __ATOMIC_ACQUIRE,
                                     __HIP_MEMORY_SCOPE_AGENT) < phase) {
                __builtin_amdgcn_s_sleep(2);
            }
        }
    }
    __syncthreads();
}

// ===========================================================================
// Fused kernel
// ===========================================================================
__global__ __launch_bounds__(512, 1) void k_all(const float* __restrict__ W,
                                                const float* __restrict__ x,
                                                const float* __restrict__ bias,
                                                unsigned short* __restrict__ priors,
                                                float* __restrict__ part,
                                                float* __restrict__ out,
                                                int* __restrict__ bar) {
    const int blk = blockIdx.x;   // 0..255
    const int t   = threadIdx.x;  // 0..511
    int* cnt = bar;
    int* gen = bar + 1;

    __shared__ float Wl[2][16 * 132];
    __shared__ float xl[2][512];
    __shared__ float noutT[16 * 64];   // [v][o]
    __shared__ float red[7 * 1088];    // waves 1..7 partials, row pad 17

    // ---------------- phase P: priors for i = blk*2 + (t>>8) ----------------
    {
        const int ih = t >> 8;     // which of the block's two i's
        const int t2 = t & 255;
        const int i  = blk * 2 + ih;

        if (t2 < 128) {
            float4v v = *(const float4v*)(x + ((size_t)(t2 >> 1) * 512 + i) * 8 + (size_t)(t2 & 1) * 4);
            *(float4v*)(xl[ih] + t2 * 4) = v;
        }
        const int r  = t2 & 15;   // o within oc-chunk
        const int bq = t2 >> 4;   // 0..15

        for (int oc = 0; oc < 4; ++oc) {
            __syncthreads();  // uniform across both halves
            #pragma unroll
            for (int kk = 0; kk < 2; ++kk) {
                int j  = t2 + kk * 256;
                int ol = j >> 5;
                int r4 = j & 31;
                float4v v = *(const float4v*)(W + ((size_t)((oc * 16 + ol) * 512 + i)) * 128 + (size_t)r4 * 4);
                *(float4v*)(Wl[ih] + ol * 132 + r4 * 4) = v;
            }
            __syncthreads();

            float4v wreg[32];
            const float4v* wp = (const float4v*)(Wl[ih] + r * 132);
            #pragma unroll
            for (int j = 0; j < 32; ++j) wreg[j] = wp[j];

            const int o = oc * 16 + r;
            #pragma unroll
            for (int kk = 0; kk < 4; ++kk) {
                const int b = bq + 16 * kk;
                float4v xr0 = ((const float4v*)(xl[ih] + b * 8))[0];
                float4v xr1 = ((const float4v*)(xl[ih] + b * 8))[1];
                ushort8 u0, u1;
                #pragma unroll
                for (int v = 0; v < 16; ++v) {
                    float s = 0.0f;
                    #pragma unroll
                    for (int l = 0; l < 8; ++l) {
                        int idx = v * 8 + l;
                        float wv = wreg[idx >> 2][idx & 3];
                        float xv = (l < 4) ? xr0[l & 3] : xr1[l & 3];
                        s = fmaf(wv, xv, s);
                    }
                    unsigned short hb = f2bf(s);
                    if (v < 8) u0[v] = hb; else u1[v - 8] = hb;
                }
                unsigned short* dst = priors + ((size_t)(b * 512 + i) * 64 + o) * 16;
                *(ushort8*)(dst) = u0;
                *(ushort8*)(dst + 8) = u1;
            }
        }
    }

    gbar(cnt, gen, 1);

    // ---------------- phase S: load fragment + i-sum -> part0 ----------------
    const int b    = blk >> 2;   // 0..63
    const int q    = blk & 3;    // i-quarter (128 i's)
    const int w    = t >> 6;     // wave 0..7
    const int lane = t & 63;     // == o

    ushort8 c0[16], c1[16];      // the thread's 16 priors i-rows (128 VGPRs)
    float acc[16];
    #pragma unroll
    for (int j = 0; j < 16; ++j) acc[j] = 0.0f;

    const unsigned short* bp = priors + (size_t)b * 524288
                             + (size_t)(q * 128 + w * 16) * 1024 + (size_t)lane * 16;
    #pragma unroll
    for (int k = 0; k < 16; ++k) {
        c0[k] = *(const ushort8*)(bp + (size_t)k * 1024);
        c1[k] = *(const ushort8*)(bp + (size_t)k * 1024 + 8);
        #pragma unroll
        for (int j = 0; j < 8; ++j) {
            acc[j]     += bf2f(c0[k][j]);
            acc[8 + j] += bf2f(c1[k][j]);
        }
    }
    if (w > 0) {
        #pragma unroll
        for (int j = 0; j < 16; ++j) red[(w - 1) * 1088 + lane * 17 + j] = acc[j];
    }
    __syncthreads();
    if (w == 0) {
        float* dst = part + (size_t)b * 4096 + (size_t)q * 1024 + lane * 16;
        #pragma unroll
        for (int j = 0; j < 16; ++j) {
            float s = acc[j];
            #pragma unroll
            for (int ww = 0; ww < 7; ++ww) s += red[ww * 1088 + lane * 17 + j];
            dst[j] = s;
        }
    }

    gbar(cnt, gen, 2);

    // ---------------- phases R0..R2: routing from registers ----------------
    for (int r = 0; r < 3; ++r) {
        const float* pprev = part + (size_t)r * 262144 + (size_t)b * 4096;
        float*       pnext = part + (size_t)(r + 1) * 262144 + (size_t)b * 4096 + (size_t)q * 1024;

        if (t < 64) {
            float vv[16]; float n2 = 0.0f;
            #pragma unroll
            for (int j = 0; j < 16; ++j) {
                float s = 0.0f;
                #pragma unroll
                for (int ic = 0; ic < 4; ++ic)
                    s += __hip_atomic_load(pprev + ic * 1024 + t * 16 + j,
                                           __ATOMIC_RELAXED, __HIP_MEMORY_SCOPE_AGENT);
                vv[j] = s; n2 += s * s;
            }
            float inv = 1.0f / fmaxf(sqrtf(n2), 1e-12f);
            #pragma unroll
            for (int j = 0; j < 16; ++j) noutT[j * 64 + t] = vv[j] * inv;
        }
        __syncthreads();

        float nr[16];
        #pragma unroll
        for (int j = 0; j < 16; ++j) nr[j] = noutT[j * 64 + lane];

        float a2[16];
        #pragma unroll
        for (int j = 0; j < 16; ++j) a2[j] = 0.0f;

        #pragma unroll
        for (int k = 0; k < 16; ++k) {
            float pf[16];
            #pragma unroll
            for (int j = 0; j < 8; ++j) { pf[j] = bf2f(c0[k][j]); pf[8 + j] = bf2f(c1[k][j]); }

            float logit = 0.0f;
            #pragma unroll
            for (int j = 0; j < 16; ++j) logit = fmaf(pf[j], nr[j], logit);

            float m = logit;
            #pragma unroll
            for (int d = 1; d < 64; d <<= 1) m = fmaxf(m, __shfl_xor(m, d));
            float e = __expf(logit - m);
            float s = e;
            #pragma unroll
            for (int d = 1; d < 64; d <<= 1) s += __shfl_xor(s, d);
            float p = e / s;

            #pragma unroll
            for (int j = 0; j < 16; ++j) a2[j] = fmaf(p, pf[j], a2[j]);
        }

        __syncthreads();  // red free (prev readers done)
        if (w > 0) {
            #pragma unroll
            for (int j = 0; j < 16; ++j) red[(w - 1) * 1088 + lane * 17 + j] = a2[j];
        }
        __syncthreads();
        if (w == 0) {
            #pragma unroll
            for (int j = 0; j < 16; ++j) {
                float s = a2[j];
                #pragma unroll
                for (int ww = 0; ww < 7; ++ww) s += red[ww * 1088 + lane * 17 + j];
                pnext[lane * 16 + j] = s;
            }
        }
        gbar(cnt, gen, 3 + r);
    }

    // ---------------- phase F: squash + bias ----------------
    if (q == 0 && t < 64) {
        const float* p3 = part + (size_t)3 * 262144 + (size_t)b * 4096;
        float vv[16]; float n2 = 0.0f;
        #pragma unroll
        for (int j = 0; j < 16; ++j) {
            float s = 0.0f;
            #pragma unroll
            for (int ic = 0; ic < 4; ++ic)
                s += __hip_atomic_load(p3 + ic * 1024 + t * 16 + j,
                                       __ATOMIC_RELAXED, __HIP_MEMORY_SCOPE_AGENT);
            vv[j] = s; n2 += s * s;
        }
        float n = sqrtf(n2);
        float sc = n / (1.0f + n2);
        float* qd = out + (size_t)b * 1024 + t * 16;
        #pragma unroll
        for (int j = 0; j < 16; ++j) qd[j] = vv[j] * sc + bias[t * 16 + j];
    }
}

// ===========================================================================
// Fallback path (verified round-5 pipeline)
// ===========================================================================
__global__ __launch_bounds__(256) void k_priors(const float* __restrict__ W,
                                                const float* __restrict__ x,
                                                unsigned short* __restrict__ priors) {
    const int i = blockIdx.x;
    const int t = threadIdx.x;
    __shared__ float Wl[16 * 132];
    __shared__ float xl[512];

    if (t < 128) {
        float4v v = *(const float4v*)(x + ((size_t)(t >> 1) * 512 + i) * 8 + (size_t)(t & 1) * 4);
        *(float4v*)(xl + t * 4) = v;
    }
    const int r  = t & 15;
    const int bq = t >> 4;

    for (int oc = 0; oc < 4; ++oc) {
        __syncthreads();
        #pragma unroll
        for (int k = 0; k < 2; ++k) {
            int j  = t + k * 256;
            int ol = j >> 5;
            int r4 = j & 31;
            float4v v = *(const float4v*)(W + ((size_t)((oc * 16 + ol) * 512 + i)) * 128 + (size_t)r4 * 4);
            *(float4v*)(Wl + ol * 132 + r4 * 4) = v;
        }
        __syncthreads();

        float4v wreg[32];
        const float4v* wp = (const float4v*)(Wl + r * 132);
        #pragma unroll
        for (int j = 0; j < 32; ++j) wreg[j] = wp[j];

        const int o = oc * 16 + r;
        #pragma unroll
        for (int k = 0; k < 4; ++k) {
            const int b = bq + 16 * k;
            float4v xr0 = ((const float4v*)(xl + b * 8))[0];
            float4v xr1 = ((const float4v*)(xl + b * 8))[1];
            ushort8 u0, u1;
            #pragma unroll
            for (int v = 0; v < 16; ++v) {
                float s = 0.0f;
                #pragma unroll
                for (int l = 0; l < 8; ++l) {
                    int idx = v * 8 + l;
                    float wv = wreg[idx >> 2][idx & 3];
                    float xv = (l < 4) ? xr0[l & 3] : xr1[l & 3];
                    s = fmaf(wv, xv, s);
                }
                unsigned short hb = f2bf(s);
                if (v < 8) u0[v] = hb; else u1[v - 8] = hb;
            }
            unsigned short* dst = priors + ((size_t)(b * 512 + i) * 64 + o) * 16;
            *(ushort8*)(dst) = u0;
            *(ushort8*)(dst + 8) = u1;
        }
    }
}

__global__ __launch_bounds__(256) void k_sum0(const unsigned short* __restrict__ priors,
                                              float* __restrict__ part0) {
    const int b    = blockIdx.x >> 4;
    const int ic   = blockIdx.x & 15;
    const int t    = threadIdx.x;
    const int slot = t & 127;
    const int io   = t >> 7;
    const int o    = slot >> 1;
    const int vh   = slot & 1;

    float acc[8];
    #pragma unroll
    for (int j = 0; j < 8; ++j) acc[j] = 0.0f;

    const unsigned short* base = priors + (size_t)b * 524288 + (size_t)o * 16 + vh * 8;
    #pragma unroll
    for (int k = 0; k < 16; ++k) {
        const int i = ic * 32 + k * 2 + io;
        ushort8 u = *(const ushort8*)(base + (size_t)i * 1024);
        #pragma unroll
        for (int j = 0; j < 8; ++j) acc[j] += bf2f(u[j]);
    }

    __shared__ float red[8 * 128];
    if (io == 1) {
        #pragma unroll
        for (int j = 0; j < 8; ++j) red[j * 128 + slot] = acc[j];
    }
    __syncthreads();
    if (io == 0) {
        float* dst = part0 + (size_t)b * 16384 + (size_t)ic * 1024 + o * 16 + vh * 8;
        #pragma unroll
        for (int j = 0; j < 8; ++j) dst[j] = acc[j] + red[j * 128 + slot];
    }
}

__global__ __launch_bounds__(256) void k_route(const unsigned short* __restrict__ priors,
                                               const float* __restrict__ part_prev,
                                               float* __restrict__ part_next) {
    const int b    = blockIdx.x >> 4;
    const int h    = blockIdx.x & 15;
    const int t    = threadIdx.x;
    const int w    = t >> 6;
    const int lane = t & 63;

    __shared__ float noutT[16 * 64];
    __shared__ float accbuf[4 * 1088];

    if (t < 64) {
        const float* pp = part_prev + (size_t)b * 16384 + t * 16;
        float4v s4[4];
        #pragma unroll
        for (int g = 0; g < 4; ++g) s4[g] = (float4v){0.f, 0.f, 0.f, 0.f};
        #pragma unroll
        for (int ic = 0; ic < 16; ++ic) {
            #pragma unroll
            for (int g = 0; g < 4; ++g)
                s4[g] += *(const float4v*)(pp + (size_t)ic * 1024 + g * 4);
        }
        float vv[16]; float n2 = 0.0f;
        #pragma unroll
        for (int j = 0; j < 16; ++j) { vv[j] = s4[j >> 2][j & 3]; n2 += vv[j] * vv[j]; }
        float inv = 1.0f / fmaxf(sqrtf(n2), 1e-12f);
        #pragma unroll
        for (int j = 0; j < 16; ++j) noutT[j * 64 + t] = vv[j] * inv;
    }
    __syncthreads();

    float nr[16];
    #pragma unroll
    for (int j = 0; j < 16; ++j) nr[j] = noutT[j * 64 + lane];

    float acc[16];
    #pragma unroll
    for (int j = 0; j < 16; ++j) acc[j] = 0.0f;

    const size_t base = (size_t)b * 524288 + (size_t)lane * 16;
    #pragma unroll
    for (int k = 0; k < 8; ++k) {
        const int i = h * 32 + w + 4 * k;
        const ushort8* pp = (const ushort8*)(priors + base + (size_t)i * 1024);
        ushort8 u0 = pp[0], u1 = pp[1];
        float pf[16];
        #pragma unroll
        for (int j = 0; j < 8; ++j) { pf[j] = bf2f(u0[j]); pf[8 + j] = bf2f(u1[j]); }

        float logit = 0.0f;
        #pragma unroll
        for (int j = 0; j < 16; ++j) logit = fmaf(pf[j], nr[j], logit);

        float m = logit;
        #pragma unroll
        for (int d = 1; d < 64; d <<= 1) m = fmaxf(m, __shfl_xor(m, d));
        float e = __expf(logit - m);
        float s = e;
        #pragma unroll
        for (int d = 1; d < 64; d <<= 1) s += __shfl_xor(s, d);
        float p = e / s;

        #pragma unroll
        for (int j = 0; j < 16; ++j) acc[j] = fmaf(p, pf[j], acc[j]);
    }

    #pragma unroll
    for (int j = 0; j < 16; ++j) accbuf[w * 1088 + lane * 17 + j] = acc[j];
    __syncthreads();

    float* dst = part_next + (size_t)b * 16384 + (size_t)h * 1024;
    for (int j = t; j < 1024; j += 256) {
        const int o = j >> 4, v = j & 15;
        const int idx = o * 17 + v;
        dst[j] = accbuf[idx] + accbuf[1088 + idx] + accbuf[2176 + idx] + accbuf[3264 + idx];
    }
}

__global__ __launch_bounds__(64) void k_fin(const float* __restrict__ part3,
                                            const float* __restrict__ bias,
                                            float* __restrict__ out) {
    const int b = blockIdx.x;
    const int o = threadIdx.x;
    const float* pp = part3 + (size_t)b * 16384 + o * 16;
    float4v s4[4];
    #pragma unroll
    for (int g = 0; g < 4; ++g) s4[g] = (float4v){0.f, 0.f, 0.f, 0.f};
    #pragma unroll
    for (int ic = 0; ic < 16; ++ic) {
        #pragma unroll
        for (int g = 0; g < 4; ++g)
            s4[g] += *(const float4v*)(pp + (size_t)ic * 1024 + g * 4);
    }
    float vv[16]; float n2 = 0.0f;
    #pragma unroll
    for (int j = 0; j < 16; ++j) { vv[j] = s4[j >> 2][j & 3]; n2 += vv[j] * vv[j]; }
    float n = sqrtf(n2);
    float scale = n / (1.0f + n2);
    float* q = out + (size_t)b * 1024 + o * 16;
    #pragma unroll
    for (int j = 0; j < 16; ++j) q[j] = vv[j] * scale + bias[o * 16 + j];
}

extern "C" void kernel_launch(void* const* d_in, const int* in_sizes, int n_in,
                              void* d_out, int out_size, void* d_ws, size_t ws_size,
                              hipStream_t stream) {
    const float* x    = (const float*)d_in[0];   // [64,512,8]
    const float* W    = (const float*)d_in[1];   // [64,512,16,8]
    const float* bias = (const float*)d_in[2];   // [64,16]
    float* out = (float*)d_out;                  // [64,64,16]

    unsigned short* priors = (unsigned short*)d_ws;                 // 67,108,864 B
    float* partF = (float*)((char*)d_ws + 67108864);                // 4 MB (fused)
    int*   bar   = (int*)((char*)d_ws + 71303168);                  // 8 B barrier
    float* partB = (float*)((char*)d_ws + 67108864);                // 16 MB (fallback; exclusive)

    // zero the barrier words each launch (graph-legal, deterministic)
    hipMemsetAsync(bar, 0, 8, stream);

    void* args[] = { (void*)&W, (void*)&x, (void*)&bias, (void*)&priors,
                     (void*)&partF, (void*)&out, (void*)&bar };
    hipError_t err = hipLaunchCooperativeKernel((const void*)k_all, dim3(256), dim3(512),
                                                args, 0, stream);
    if (err != hipSuccess) {
        (void)hipGetLastError();  // clear error state
        float* p0 = partB;
        float* p1 = partB + 1048576;
        float* p2 = partB + 2 * 1048576;
        float* p3 = partB + 3 * 1048576;
        k_priors<<<512, 256, 0, stream>>>(W, x, priors);
        k_sum0  <<<1024, 256, 0, stream>>>(priors, p0);
        k_route <<<1024, 256, 0, stream>>>(priors, p0, p1);
        k_route <<<1024, 256, 0, stream>>>(priors, p1, p2);
        k_route <<<1024, 256, 0, stream>>>(priors, p2, p3);
        k_fin   <<<64, 64, 0, stream>>>(p3, bias, out);
    }
}

// Round 10
// 189.159 us; speedup vs baseline: 3.0411x; 2.0310x over previous
//
#include <hip/hip_runtime.h>
#include <hip/hip_bf16.h>
#include <cstdint>

// CapsuleLinear: B=64, I=512, O=64, LIN=8, LOUT=16, 3 routing iterations.
// x: [64,512,8] f32, W: [64,512,16,8] f32, bias: [64,16] f32, out: [64,64,16] f32.
//
// ROUND 10: cooperative/fused path abandoned (5 rounds: spills at a pinned
// 128-VGPR cap, then a co-residency deadlock). This is the verified round-5
// multi-kernel pipeline with two structural cuts:
//  1) k_pri_sum: priors einsum AND the i-partial sums (part0) in ONE kernel.
//     Grid (ic:16 x bg:16); block owns 32 i x 4 b x all (o,v). Removes the
//     67MB sum0 read pass + one launch gap. W re-reads are L2/L3-resident.
//  2) k_route_fin: last routing iteration + squash/bias fused via a per-b
//     last-arriver counter (no spin waits -> no deadlock; memset per launch
//     -> graph-replay deterministic).
// Launches: memset(256B), k_pri_sum, k_route, k_route, k_route_fin.
//
// ws layout: priors bf16 [b][i][o][v]  67,108,864 B
//   part0/part3(aliased) @ +67,108,864   4,194,304 B   [64][16][1024] f32
//   part1               @ +71,303,168   4,194,304 B
//   part2               @ +75,497,472   4,194,304 B
//   bcnt[64] int        @ +79,691,776         256 B
// Total 79,692,032 B (< proven 83,886,080 ws floor).

typedef float float4v __attribute__((ext_vector_type(4)));
typedef unsigned short ushort8 __attribute__((ext_vector_type(8)));
typedef unsigned short ushort4v __attribute__((ext_vector_type(4)));

__device__ __forceinline__ float bf2f(unsigned short u) {
    union { unsigned int ui; float f; } cv;
    cv.ui = ((unsigned int)u) << 16;
    return cv.f;
}
__device__ __forceinline__ unsigned short f2bf(float f) {
    union { float f; unsigned int ui; } cv;
    cv.f = f;
    unsigned int u = cv.ui;
    unsigned int r = u + 0x7FFFu + ((u >> 16) & 1u);  // RNE
    return (unsigned short)(r >> 16);
}

// ---------------------------------------------------------------------------
// K_pri_sum: priors[b,i,o,v] = sum_l W[o,i,v,l]*x[b,i,l] (bf16 store) AND
// part0[b][ic][o*16+v] = sum over the chunk's 32 i's (fp32, register acc).
// Grid 256 = (bg:16 b-group of 4) x (ic:16 chunk of 32 i).
// Thread = (o = t>>2, vh = t&3 v-quad). Exclusive writes, no atomics.
// ---------------------------------------------------------------------------
__global__ __launch_bounds__(256) void k_pri_sum(const float* __restrict__ W,
                                                 const float* __restrict__ x,
                                                 unsigned short* __restrict__ priors,
                                                 float* __restrict__ part0) {
    const int ic = blockIdx.x & 15;
    const int bg = blockIdx.x >> 4;
    const int t  = threadIdx.x;
    const int o  = t >> 2;   // 0..63
    const int vh = t & 3;    // v-quad: v = vh*4 .. vh*4+3

    __shared__ float xl[4][32][8];   // [b_l][i_l][l]
    {
        const int bl  = t >> 6;
        const int il  = (t & 63) >> 1;
        const int hf  = t & 1;
        const float* src = x + ((size_t)((bg * 4 + bl) * 512 + ic * 32 + il)) * 8 + hf * 4;
        *(float4v*)(&xl[bl][il][hf * 4]) = *(const float4v*)src;
    }
    __syncthreads();

    float4v acc[4];   // [b_l] -> 4 v's
    #pragma unroll
    for (int j = 0; j < 4; ++j) acc[j] = (float4v){0.f, 0.f, 0.f, 0.f};

    const float* wbase = W + (size_t)o * 65536 + (size_t)(ic * 32) * 128 + vh * 32;

    for (int il = 0; il < 32; ++il) {
        float4v wq[8];   // v_l 0..3 x l 0..7  (128B contiguous)
        #pragma unroll
        for (int j = 0; j < 8; ++j) wq[j] = *(const float4v*)(wbase + (size_t)il * 128 + j * 4);
        const int i = ic * 32 + il;
        #pragma unroll
        for (int bl = 0; bl < 4; ++bl) {
            float4v xr0 = *(const float4v*)(&xl[bl][il][0]);
            float4v xr1 = *(const float4v*)(&xl[bl][il][4]);
            ushort4v u;
            #pragma unroll
            for (int v = 0; v < 4; ++v) {
                float s = 0.0f;
                #pragma unroll
                for (int l = 0; l < 8; ++l) {
                    float wv = wq[v * 2 + (l >> 2)][l & 3];
                    float xv = (l < 4) ? xr0[l & 3] : xr1[l & 3];
                    s = fmaf(wv, xv, s);
                }
                acc[bl][v] += s;
                u[v] = f2bf(s);
            }
            unsigned short* dst = priors
                + ((size_t)((bg * 4 + bl) * 512 + i) * 64 + o) * 16 + vh * 4;
            *(ushort4v*)dst = u;
        }
    }

    #pragma unroll
    for (int bl = 0; bl < 4; ++bl) {
        float* dst = part0 + (size_t)(bg * 4 + bl) * 16384 + (size_t)ic * 1024
                   + o * 16 + vh * 4;
        *(float4v*)dst = acc[bl];
    }
}

// ---------------------------------------------------------------------------
// K_route: one routing iteration (verified round-5 kernel).
// Grid 1024 = (b:64) x (h:16); 4 waves; wave w owns i = h*32 + w + 4k.
// lane == o; softmax over o is a wave shuffle-reduce.
// ---------------------------------------------------------------------------
__global__ __launch_bounds__(256) void k_route(const unsigned short* __restrict__ priors,
                                               const float* __restrict__ part_prev,
                                               float* __restrict__ part_next) {
    const int b    = blockIdx.x >> 4;
    const int h    = blockIdx.x & 15;
    const int t    = threadIdx.x;
    const int w    = t >> 6;
    const int lane = t & 63;

    __shared__ float noutT[16 * 64];
    __shared__ float accbuf[4 * 1088];

    if (t < 64) {
        const float* pp = part_prev + (size_t)b * 16384 + t * 16;
        float4v s4[4];
        #pragma unroll
        for (int g = 0; g < 4; ++g) s4[g] = (float4v){0.f, 0.f, 0.f, 0.f};
        #pragma unroll
        for (int ic = 0; ic < 16; ++ic) {
            #pragma unroll
            for (int g = 0; g < 4; ++g)
                s4[g] += *(const float4v*)(pp + (size_t)ic * 1024 + g * 4);
        }
        float vv[16]; float n2 = 0.0f;
        #pragma unroll
        for (int j = 0; j < 16; ++j) { vv[j] = s4[j >> 2][j & 3]; n2 += vv[j] * vv[j]; }
        float inv = 1.0f / fmaxf(sqrtf(n2), 1e-12f);
        #pragma unroll
        for (int j = 0; j < 16; ++j) noutT[j * 64 + t] = vv[j] * inv;
    }
    __syncthreads();

    float nr[16];
    #pragma unroll
    for (int j = 0; j < 16; ++j) nr[j] = noutT[j * 64 + lane];

    float acc[16];
    #pragma unroll
    for (int j = 0; j < 16; ++j) acc[j] = 0.0f;

    const size_t base = (size_t)b * 524288 + (size_t)lane * 16;
    #pragma unroll
    for (int k = 0; k < 8; ++k) {
        const int i = h * 32 + w + 4 * k;
        const ushort8* pp = (const ushort8*)(priors + base + (size_t)i * 1024);
        ushort8 u0 = pp[0], u1 = pp[1];
        float pf[16];
        #pragma unroll
        for (int j = 0; j < 8; ++j) { pf[j] = bf2f(u0[j]); pf[8 + j] = bf2f(u1[j]); }

        float logit = 0.0f;
        #pragma unroll
        for (int j = 0; j < 16; ++j) logit = fmaf(pf[j], nr[j], logit);

        float m = logit;
        #pragma unroll
        for (int d = 1; d < 64; d <<= 1) m = fmaxf(m, __shfl_xor(m, d));
        float e = __expf(logit - m);
        float s = e;
        #pragma unroll
        for (int d = 1; d < 64; d <<= 1) s += __shfl_xor(s, d);
        float p = e / s;

        #pragma unroll
        for (int j = 0; j < 16; ++j) acc[j] = fmaf(p, pf[j], acc[j]);
    }

    #pragma unroll
    for (int j = 0; j < 16; ++j) accbuf[w * 1088 + lane * 17 + j] = acc[j];
    __syncthreads();

    float* dst = part_next + (size_t)b * 16384 + (size_t)h * 1024;
    for (int j = t; j < 1024; j += 256) {
        const int o = j >> 4, v = j & 15;
        const int idx = o * 17 + v;
        dst[j] = accbuf[idx] + accbuf[1088 + idx] + accbuf[2176 + idx] + accbuf[3264 + idx];
    }
}

// ---------------------------------------------------------------------------
// K_route_fin: last routing iteration + fused squash/bias.
// Same as k_route, then: per-b arrival counter; the 16th (last) block of
// each b reads the 16 part3 chunks, squashes, adds bias, writes d_out.
// ---------------------------------------------------------------------------
__global__ __launch_bounds__(256) void k_route_fin(const unsigned short* __restrict__ priors,
                                                   const float* __restrict__ part_prev,
                                                   float* __restrict__ part_next,
                                                   const float* __restrict__ bias,
                                                   float* __restrict__ out,
                                                   int* __restrict__ bcnt) {
    const int b    = blockIdx.x >> 4;
    const int h    = blockIdx.x & 15;
    const int t    = threadIdx.x;
    const int w    = t >> 6;
    const int lane = t & 63;

    __shared__ float noutT[16 * 64];
    __shared__ float accbuf[4 * 1088];
    __shared__ int islast;

    if (t < 64) {
        const float* pp = part_prev + (size_t)b * 16384 + t * 16;
        float4v s4[4];
        #pragma unroll
        for (int g = 0; g < 4; ++g) s4[g] = (float4v){0.f, 0.f, 0.f, 0.f};
        #pragma unroll
        for (int ic = 0; ic < 16; ++ic) {
            #pragma unroll
            for (int g = 0; g < 4; ++g)
                s4[g] += *(const float4v*)(pp + (size_t)ic * 1024 + g * 4);
        }
        float vv[16]; float n2 = 0.0f;
        #pragma unroll
        for (int j = 0; j < 16; ++j) { vv[j] = s4[j >> 2][j & 3]; n2 += vv[j] * vv[j]; }
        float inv = 1.0f / fmaxf(sqrtf(n2), 1e-12f);
        #pragma unroll
        for (int j = 0; j < 16; ++j) noutT[j * 64 + t] = vv[j] * inv;
    }
    __syncthreads();

    float nr[16];
    #pragma unroll
    for (int j = 0; j < 16; ++j) nr[j] = noutT[j * 64 + lane];

    float acc[16];
    #pragma unroll
    for (int j = 0; j < 16; ++j) acc[j] = 0.0f;

    const size_t base = (size_t)b * 524288 + (size_t)lane * 16;
    #pragma unroll
    for (int k = 0; k < 8; ++k) {
        const int i = h * 32 + w + 4 * k;
        const ushort8* pp = (const ushort8*)(priors + base + (size_t)i * 1024);
        ushort8 u0 = pp[0], u1 = pp[1];
        float pf[16];
        #pragma unroll
        for (int j = 0; j < 8; ++j) { pf[j] = bf2f(u0[j]); pf[8 + j] = bf2f(u1[j]); }

        float logit = 0.0f;
        #pragma unroll
        for (int j = 0; j < 16; ++j) logit = fmaf(pf[j], nr[j], logit);

        float m = logit;
        #pragma unroll
        for (int d = 1; d < 64; d <<= 1) m = fmaxf(m, __shfl_xor(m, d));
        float e = __expf(logit - m);
        float s = e;
        #pragma unroll
        for (int d = 1; d < 64; d <<= 1) s += __shfl_xor(s, d);
        float p = e / s;

        #pragma unroll
        for (int j = 0; j < 16; ++j) acc[j] = fmaf(p, pf[j], acc[j]);
    }

    #pragma unroll
    for (int j = 0; j < 16; ++j) accbuf[w * 1088 + lane * 17 + j] = acc[j];
    __syncthreads();

    float* dst = part_next + (size_t)b * 16384 + (size_t)h * 1024;
    for (int j = t; j < 1024; j += 256) {
        const int o = j >> 4, v = j & 15;
        const int idx = o * 17 + v;
        dst[j] = accbuf[idx] + accbuf[1088 + idx] + accbuf[2176 + idx] + accbuf[3264 + idx];
    }

    // --- last-arriver fin for this b ---
    __syncthreads();   // drain this block's dst stores (barrier implies waitcnt)
    if (t == 0) {
        __threadfence();
        int old = __hip_atomic_fetch_add(&bcnt[b], 1, __ATOMIC_ACQ_REL,
                                         __HIP_MEMORY_SCOPE_AGENT);
        islast = (old == 15) ? 1 : 0;
    }
    __syncthreads();
    if (islast && t < 64) {
        const float* p3 = part_next + (size_t)b * 16384 + t * 16;
        float vv[16]; float n2 = 0.0f;
        #pragma unroll
        for (int j = 0; j < 16; ++j) {
            float s = 0.0f;
            #pragma unroll
            for (int ic = 0; ic < 16; ++ic)
                s += __hip_atomic_load(p3 + (size_t)ic * 1024 + j,
                                       __ATOMIC_RELAXED, __HIP_MEMORY_SCOPE_AGENT);
            vv[j] = s; n2 += s * s;
        }
        float n = sqrtf(n2);
        float sc = n / (1.0f + n2);
        float* qd = out + (size_t)b * 1024 + t * 16;
        #pragma unroll
        for (int j = 0; j < 16; ++j) qd[j] = vv[j] * sc + bias[t * 16 + j];
    }
}

extern "C" void kernel_launch(void* const* d_in, const int* in_sizes, int n_in,
                              void* d_out, int out_size, void* d_ws, size_t ws_size,
                              hipStream_t stream) {
    const float* x    = (const float*)d_in[0];   // [64,512,8]
    const float* W    = (const float*)d_in[1];   // [64,512,16,8]
    const float* bias = (const float*)d_in[2];   // [64,16]
    float* out = (float*)d_out;                  // [64,64,16]

    unsigned short* priors = (unsigned short*)d_ws;            // 67,108,864 B
    float* p0 = (float*)((char*)d_ws + 67108864);              // 4 MB (also p3)
    float* p1 = (float*)((char*)d_ws + 71303168);              // 4 MB
    float* p2 = (float*)((char*)d_ws + 75497472);              // 4 MB
    int* bcnt = (int*)((char*)d_ws + 79691776);                // 256 B
    float* p3 = p0;   // part0 is dead after route0 -> reuse for part3

    hipMemsetAsync(bcnt, 0, 256, stream);
    k_pri_sum  <<<256,  256, 0, stream>>>(W, x, priors, p0);
    k_route    <<<1024, 256, 0, stream>>>(priors, p0, p1);
    k_route    <<<1024, 256, 0, stream>>>(priors, p1, p2);
    k_route_fin<<<1024, 256, 0, stream>>>(priors, p2, p3, bias, out, bcnt);
}

// Round 11
// 141.630 us; speedup vs baseline: 4.0616x; 1.3356x over previous
//
#include <hip/hip_runtime.h>
#include <hip/hip_bf16.h>
#include <cstdint>

// CapsuleLinear: B=64, I=512, O=64, LIN=8, LOUT=16, 3 routing iterations.
// x: [64,512,8] f32, W: [64,512,16,8] f32, bias: [64,16] f32, out: [64,64,16] f32.
//
// ROUND 11: two kernels, zero cross-block synchronization primitives.
// Round-10 post-mortem: fused-fin's per-block __threadfence (agent fence =
// L2 writeback on 8-XCD part) + scalar atomic-load sweep cost ~93us of idle
// tail. Kernel boundaries provide coherence ~for free; the only cross-block
// dependency (sum over I per b) is eliminated by giving each block ALL of b.
//
//  K1 k_pri_sum (verified round 10, absmax 0.0039): grid 256 = (ic:16, bg:16);
//     priors[b,i,o,v] = sum_l W[o,i,v,l]*x[b,i,l] -> bf16, and the 32-i
//     partial sums -> part0[b][ic][o*16+v] from register accumulators.
//  K2 k_route_all: grid 64 (one block per b), 1024 thr (wave w: i in
//     [32w,32w+32), lane = o). sum(part0) -> 3x {normalize -> logits ->
//     wave-softmax over o -> weighted sum, LDS wave-reduce} -> squash+bias.
//     priors[b] (1MB) re-streamed from L2/L3 per iteration.
//
// ws: priors bf16 67,108,864 B | part0 [64][16][1024] f32 4,194,304 B.

typedef float float4v __attribute__((ext_vector_type(4)));
typedef unsigned short ushort8 __attribute__((ext_vector_type(8)));
typedef unsigned short ushort4v __attribute__((ext_vector_type(4)));

__device__ __forceinline__ float bf2f(unsigned short u) {
    union { unsigned int ui; float f; } cv;
    cv.ui = ((unsigned int)u) << 16;
    return cv.f;
}
__device__ __forceinline__ unsigned short f2bf(float f) {
    union { float f; unsigned int ui; } cv;
    cv.f = f;
    unsigned int u = cv.ui;
    unsigned int r = u + 0x7FFFu + ((u >> 16) & 1u);  // RNE
    return (unsigned short)(r >> 16);
}

// ---------------------------------------------------------------------------
// K1: priors einsum + 32-i partial sums (verified round 10).
// Grid 256 = (bg:16 b-group of 4) x (ic:16 chunk of 32 i).
// Thread = (o = t>>2, vh = t&3 v-quad). Exclusive writes, no atomics.
// ---------------------------------------------------------------------------
__global__ __launch_bounds__(256) void k_pri_sum(const float* __restrict__ W,
                                                 const float* __restrict__ x,
                                                 unsigned short* __restrict__ priors,
                                                 float* __restrict__ part0) {
    const int ic = blockIdx.x & 15;
    const int bg = blockIdx.x >> 4;
    const int t  = threadIdx.x;
    const int o  = t >> 2;   // 0..63
    const int vh = t & 3;    // v-quad: v = vh*4 .. vh*4+3

    __shared__ float xl[4][32][8];   // [b_l][i_l][l]
    {
        const int bl  = t >> 6;
        const int il  = (t & 63) >> 1;
        const int hf  = t & 1;
        const float* src = x + ((size_t)((bg * 4 + bl) * 512 + ic * 32 + il)) * 8 + hf * 4;
        *(float4v*)(&xl[bl][il][hf * 4]) = *(const float4v*)src;
    }
    __syncthreads();

    float4v acc[4];
    #pragma unroll
    for (int j = 0; j < 4; ++j) acc[j] = (float4v){0.f, 0.f, 0.f, 0.f};

    const float* wbase = W + (size_t)o * 65536 + (size_t)(ic * 32) * 128 + vh * 32;

    for (int il = 0; il < 32; ++il) {
        float4v wq[8];
        #pragma unroll
        for (int j = 0; j < 8; ++j) wq[j] = *(const float4v*)(wbase + (size_t)il * 128 + j * 4);
        const int i = ic * 32 + il;
        #pragma unroll
        for (int bl = 0; bl < 4; ++bl) {
            float4v xr0 = *(const float4v*)(&xl[bl][il][0]);
            float4v xr1 = *(const float4v*)(&xl[bl][il][4]);
            ushort4v u;
            #pragma unroll
            for (int v = 0; v < 4; ++v) {
                float s = 0.0f;
                #pragma unroll
                for (int l = 0; l < 8; ++l) {
                    float wv = wq[v * 2 + (l >> 2)][l & 3];
                    float xv = (l < 4) ? xr0[l & 3] : xr1[l & 3];
                    s = fmaf(wv, xv, s);
                }
                acc[bl][v] += s;
                u[v] = f2bf(s);
            }
            unsigned short* dst = priors
                + ((size_t)((bg * 4 + bl) * 512 + i) * 64 + o) * 16 + vh * 4;
            *(ushort4v*)dst = u;
        }
    }

    #pragma unroll
    for (int bl = 0; bl < 4; ++bl) {
        float* dst = part0 + (size_t)(bg * 4 + bl) * 16384 + (size_t)ic * 1024
                   + o * 16 + vh * 4;
        *(float4v*)dst = acc[bl];
    }
}

// ---------------------------------------------------------------------------
// K2: all routing + fin for one b, entirely in-block.
// 1024 threads = 16 waves; wave w owns i in [32w, 32w+32); lane = o.
// LDS: sumv[1024] + noutT[1024] + red[16][1088] = ~78 KB.
// ---------------------------------------------------------------------------
__global__ __launch_bounds__(1024) void k_route_all(const unsigned short* __restrict__ priors,
                                                    const float* __restrict__ part0,
                                                    const float* __restrict__ bias,
                                                    float* __restrict__ out) {
    const int b    = blockIdx.x;     // 0..63
    const int t    = threadIdx.x;    // 0..1023
    const int w    = t >> 6;         // wave 0..15
    const int lane = t & 63;         // == o

    __shared__ float sumv[1024];       // current out_r, [o*16+v]
    __shared__ float noutT[16 * 64];   // normalized, [v][o]
    __shared__ float red[16 * 1088];   // per-wave partials, [w][o*17+v]

    // ---- initial sum: out0 = sum_ic part0[b][ic] ----
    {
        const float* pp = part0 + (size_t)b * 16384 + t;
        float s = 0.0f;
        #pragma unroll
        for (int ic = 0; ic < 16; ++ic) s += pp[(size_t)ic * 1024];
        sumv[t] = s;
    }
    __syncthreads();

    const unsigned short* bp = priors + (size_t)b * 524288
                             + (size_t)(w * 32) * 1024 + (size_t)lane * 16;

    for (int r = 0; r < 3; ++r) {
        // normalize sumv -> noutT
        if (t < 64) {
            float vv[16]; float n2 = 0.0f;
            #pragma unroll
            for (int j = 0; j < 16; ++j) { vv[j] = sumv[t * 16 + j]; n2 += vv[j] * vv[j]; }
            float inv = 1.0f / fmaxf(sqrtf(n2), 1e-12f);
            #pragma unroll
            for (int j = 0; j < 16; ++j) noutT[j * 64 + t] = vv[j] * inv;
        }
        __syncthreads();

        float nr[16];
        #pragma unroll
        for (int j = 0; j < 16; ++j) nr[j] = noutT[j * 64 + lane];

        float a2[16];
        #pragma unroll
        for (int j = 0; j < 16; ++j) a2[j] = 0.0f;

        for (int k = 0; k < 32; ++k) {
            const ushort8* pp = (const ushort8*)(bp + (size_t)k * 1024);
            ushort8 u0 = pp[0], u1 = pp[1];
            float pf[16];
            #pragma unroll
            for (int j = 0; j < 8; ++j) { pf[j] = bf2f(u0[j]); pf[8 + j] = bf2f(u1[j]); }

            float logit = 0.0f;
            #pragma unroll
            for (int j = 0; j < 16; ++j) logit = fmaf(pf[j], nr[j], logit);

            float m = logit;
            #pragma unroll
            for (int d = 1; d < 64; d <<= 1) m = fmaxf(m, __shfl_xor(m, d));
            float e = __expf(logit - m);
            float s = e;
            #pragma unroll
            for (int d = 1; d < 64; d <<= 1) s += __shfl_xor(s, d);
            float p = e / s;

            #pragma unroll
            for (int j = 0; j < 16; ++j) a2[j] = fmaf(p, pf[j], a2[j]);
        }

        // wave partials -> LDS -> new sumv
        #pragma unroll
        for (int j = 0; j < 16; ++j) red[w * 1088 + lane * 17 + j] = a2[j];
        __syncthreads();
        {
            const int o = t >> 4, v = t & 15;
            float s = 0.0f;
            #pragma unroll
            for (int w2 = 0; w2 < 16; ++w2) s += red[w2 * 1088 + o * 17 + v];
            sumv[t] = s;
        }
        __syncthreads();
    }

    // ---- fin: squash + bias ----
    if (t < 64) {
        float vv[16]; float n2 = 0.0f;
        #pragma unroll
        for (int j = 0; j < 16; ++j) { vv[j] = sumv[t * 16 + j]; n2 += vv[j] * vv[j]; }
        float n = sqrtf(n2);
        float sc = n / (1.0f + n2);
        float* qd = out + (size_t)b * 1024 + t * 16;
        #pragma unroll
        for (int j = 0; j < 16; ++j) qd[j] = vv[j] * sc + bias[t * 16 + j];
    }
}

extern "C" void kernel_launch(void* const* d_in, const int* in_sizes, int n_in,
                              void* d_out, int out_size, void* d_ws, size_t ws_size,
                              hipStream_t stream) {
    const float* x    = (const float*)d_in[0];   // [64,512,8]
    const float* W    = (const float*)d_in[1];   // [64,512,16,8]
    const float* bias = (const float*)d_in[2];   // [64,16]
    float* out = (float*)d_out;                  // [64,64,16]

    unsigned short* priors = (unsigned short*)d_ws;            // 67,108,864 B
    float* part0 = (float*)((char*)d_ws + 67108864);           // 4,194,304 B

    k_pri_sum  <<<256, 256,  0, stream>>>(W, x, priors, part0);
    k_route_all<<<64,  1024, 0, stream>>>(priors, part0, bias, out);
}